// Round 1
// baseline (651.702 us; speedup 1.0000x reference)
//
#include <hip/hip_runtime.h>
#include <hip/hip_bf16.h>

// PartialSum: x[B=2048, P=1024 * L=64] fp32 -> out[B, P] = sum over each
// contiguous 64-element partition.
//
// Memory-bound: 512 MiB read + 8 MiB write. Strategy: 16 lanes per
// partition, one float4 per lane -> fully coalesced 1 KiB/wave-instruction
// reads, then a 16-lane shfl_xor butterfly reduction. One thread per float4
// of the input, grid divides exactly (2^25 threads / 256 = 131072 blocks).

__global__ __launch_bounds__(256) void PartialSum_85478439125876_kernel(
    const float4* __restrict__ x4, float* __restrict__ out, long long n4) {
    long long tid = (long long)blockIdx.x * blockDim.x + threadIdx.x;
    if (tid >= n4) return;  // exact divide in practice; cheap guard

    float4 v = x4[tid];
    float s = v.x + v.y + v.z + v.w;

    // Reduce across the 16 lanes that share one partition.
    s += __shfl_xor(s, 1, 64);
    s += __shfl_xor(s, 2, 64);
    s += __shfl_xor(s, 4, 64);
    s += __shfl_xor(s, 8, 64);

    if ((threadIdx.x & 15) == 0) {
        out[tid >> 4] = s;
    }
}

extern "C" void kernel_launch(void* const* d_in, const int* in_sizes, int n_in,
                              void* d_out, int out_size, void* d_ws, size_t ws_size,
                              hipStream_t stream) {
    const float* x = (const float*)d_in[0];
    float* out = (float*)d_out;

    long long n = (long long)in_sizes[0];   // 2048 * 65536
    long long n4 = n / 4;                   // float4 count = 33,554,432

    const int BLOCK = 256;
    long long grid = (n4 + BLOCK - 1) / BLOCK;  // 131072

    PartialSum_85478439125876_kernel<<<(unsigned)grid, BLOCK, 0, stream>>>(
        (const float4*)x, out, n4);
}